// Round 14
// baseline (367.229 us; speedup 1.0000x reference)
//
#include <hip/hip_runtime.h>

typedef _Float16 half8 __attribute__((ext_vector_type(8)));
typedef float f32x4 __attribute__((ext_vector_type(4)));

#define H    4096
#define NE   160
#define BM   32
#define TPB  512
#define NXT  8             // outer x-tiles (BK = 512 floats each)
#define NWC  8             // W chunks per x-tile (2 k-steps of 32 each)

// d_out layout (all float32): [0,98304) topk_idx, [98304,196608) topk_weight, [196608] aux_loss

// ---- prep: w[160][4096] fp32 -> k-step-major fragment pairs (w*64 = hi + lo/2048) ----
// half8 index for (ks, h, t10, lane): (ks*20 + h*10 + t10)*64 + lane
// holds expert e = t10*16 + (lane&15), k = ks*32 + (lane>>4)*8 .. +8
__global__ __launch_bounds__(256) void prep_kernel(
    const float* __restrict__ w, _Float16* __restrict__ Wf)
{
    int F    = blockIdx.x * 256 + threadIdx.x;   // 0..81919
    int lane = F & 63;
    int t10  = (F >> 6) % 10;
    int ks   = F / 640;
    int e    = t10 * 16 + (lane & 15);
    int k0   = ks * 32 + (lane >> 4) * 8;
    const float* p = w + (size_t)e * H + k0;
    float4 v0 = *(const float4*)p;
    float4 v1 = *(const float4*)(p + 4);
    float vv[8] = {v0.x, v0.y, v0.z, v0.w, v1.x, v1.y, v1.z, v1.w};
    half8 h0, h1;
#pragma unroll
    for (int j = 0; j < 8; ++j) {
        float s = vv[j] * 64.f;
        _Float16 a = (_Float16)s;
        h0[j] = a;
        h1[j] = (_Float16)((s - (float)a) * 2048.f);
    }
    half8* out = (half8*)Wf;
    out[(ks * 20 + t10) * 64 + lane]      = h0;   // hi
    out[(ks * 20 + 10 + t10) * 64 + lane] = h1;   // lo
}

#define GLOAD_LDS(SRC, DST)                                                    \
    __builtin_amdgcn_global_load_lds(                                          \
        (const __attribute__((address_space(1))) unsigned int*)(SRC),          \
        (__attribute__((address_space(3))) unsigned int*)(DST), 16, 0, 0)

#define CONVERT(U0, U1)                                                        \
    do {                                                                       \
        float v0=U0.x, v1=U0.y, v2=U0.z, v3=U0.w;                              \
        float v4=U1.x, v5=U1.y, v6=U1.z, v7=U1.w;                              \
        _Float16 h;                                                            \
        h=(_Float16)v0; a0[0]=h; a1[0]=(_Float16)((v0-(float)h)*2048.f);       \
        h=(_Float16)v1; a0[1]=h; a1[1]=(_Float16)((v1-(float)h)*2048.f);       \
        h=(_Float16)v2; a0[2]=h; a1[2]=(_Float16)((v2-(float)h)*2048.f);       \
        h=(_Float16)v3; a0[3]=h; a1[3]=(_Float16)((v3-(float)h)*2048.f);       \
        h=(_Float16)v4; a0[4]=h; a1[4]=(_Float16)((v4-(float)h)*2048.f);       \
        h=(_Float16)v5; a0[5]=h; a1[5]=(_Float16)((v5-(float)h)*2048.f);       \
        h=(_Float16)v6; a0[6]=h; a1[6]=(_Float16)((v6-(float)h)*2048.f);       \
        h=(_Float16)v7; a0[7]=h; a1[7]=(_Float16)((v7-(float)h)*2048.f);       \
    } while (0)

__global__ __launch_bounds__(TPB) void gate_kernel(
    const float* __restrict__ x, const _Float16* __restrict__ Wf,
    float* __restrict__ outIdx, float* __restrict__ outW,
    float* __restrict__ gcnt, float* __restrict__ gssum)
{
    __shared__ __align__(16) float    s_x[BM * 512];   // 64 KB x-tile (swizzled cols)
    __shared__ __align__(16) _Float16 s_w[2560 * 8];   // 40 KB W chunk (2 k-steps)
    __shared__ float s_log[BM * 161];                  // 20.6 KB logits
    __shared__ float s_mx[BM], s_inv[BM];
    __shared__ int   s_cnt[NE];

    const int tid  = threadIdx.x;
    const int lane = tid & 63;
    const int wv   = tid >> 6;        // 8 waves: kh(2) x mh(2) x nh(2)
    const int kh   = wv >> 2;
    const int mh   = (wv >> 1) & 1;
    const int nh   = wv & 1;
    const int row0 = blockIdx.x * BM;

    if (tid < NE) s_cnt[tid] = 0;

    f32x4 accH[5], accL[5];
#pragma unroll
    for (int t = 0; t < 5; ++t) { accH[t] = (f32x4){0,0,0,0}; accL[t] = (f32x4){0,0,0,0}; }

    const int arow  = mh * 16 + (lane & 15);
    const int aswz  = (arow & 7) << 4;                 // byte-XOR for bank spread
    const int sbase = kh * 1280 + nh * 320 + lane;     // half8 index of first hi frag
    const char* Ar  = (const char*)(s_x + arow * 512);

    for (int xt = 0; xt < NXT; ++xt) {
        __syncthreads();   // all reads of s_x and s_w from previous xt complete

        // ---- stage x-tile: 32 rows x 2KB contiguous per row (64 KB, 8 DMA rounds)
        // LDS[row][c16] = global[row][c16 ^ (row&7)]  (16B units) -> linear DMA dest
#pragma unroll
        for (int rd = 0; rd < 8; ++rd) {
            int ii  = rd * 512 + tid;          // 16B unit index in tile
            int row = ii >> 7;                 // 128 x 16B per row
            int c16 = ii & 127;
            const float* src = x + (size_t)(row0 + row) * H + xt * 512
                               + ((c16 ^ (row & 7)) << 2);
            GLOAD_LDS(src, s_x + ii * 4);
        }

        for (int wc = 0; wc < NWC; ++wc) {
            if (wc) __syncthreads();   // previous W-chunk reads complete

            // ---- stage W chunk (2 k-steps, 40 KB, 5 DMA rounds) ----
            {
                const _Float16* src = Wf + ((size_t)(xt * NWC + wc) * 2560 + tid) * 8;
                _Float16*       dst = s_w + (size_t)tid * 8;
#pragma unroll
                for (int i = 0; i < 5; ++i)
                    GLOAD_LDS(src + i * 4096, dst + i * 4096);
            }
            __syncthreads();   // drain: W chunk (and x-tile when wc==0) resident

            // ---- compute this wave's k-step (wc*2 + kh) ----
            const int acolb = (wc * 2 + kh) * 128 + (lane >> 4) * 32;
            float4 u0 = *(const float4*)(Ar + ((acolb)      ^ aswz));
            float4 u1 = *(const float4*)(Ar + ((acolb + 16) ^ aswz));

            const half8* B = (const half8*)s_w + sbase;
            half8 b0[5], b1[5];
#pragma unroll
            for (int t = 0; t < 5; ++t) { b0[t] = B[t * 64]; b1[t] = B[640 + t * 64]; }

            half8 a0, a1;
            CONVERT(u0, u1);
#pragma unroll
            for (int t = 0; t < 5; ++t) {
                accH[t] = __builtin_amdgcn_mfma_f32_16x16x32_f16(a0, b0[t], accH[t], 0, 0, 0);
                accL[t] = __builtin_amdgcn_mfma_f32_16x16x32_f16(a1, b0[t], accL[t], 0, 0, 0);
                accL[t] = __builtin_amdgcn_mfma_f32_16x16x32_f16(a0, b1[t], accL[t], 0, 0, 0);
            }
        }
    }
    __syncthreads();

    // ---- K-combine into s_log; C layout col=lane&15, row=(lane>>4)*4+reg ----
    const int crow  = mh * 16 + (lane >> 4) * 4;
    const int ccol0 = nh * 80 + (lane & 15);
    if (kh == 0) {
#pragma unroll
        for (int t = 0; t < 5; ++t)
#pragma unroll
            for (int r = 0; r < 4; ++r)
                s_log[(crow + r) * 161 + ccol0 + t * 16] =
                    (accH[t][r] + accL[t][r] * (1.0f / 2048.f)) * (1.0f / 64.f);
    }
    __syncthreads();
    if (kh == 1) {
#pragma unroll
        for (int t = 0; t < 5; ++t)
#pragma unroll
            for (int r = 0; r < 4; ++r)
                s_log[(crow + r) * 161 + ccol0 + t * 16] +=
                    (accH[t][r] + accL[t][r] * (1.0f / 2048.f)) * (1.0f / 64.f);
    }
    __syncthreads();

    // ---- per-token softmax + group top-3 + expert top-6 (threads 0..31) ----
    if (tid < BM) {
        const float* L = &s_log[tid * 161];
        float gmax[8];
        float mx = -3.4e38f;
#pragma unroll
        for (int g = 0; g < 8; ++g) {
            float m = L[g * 20];
            for (int j = 1; j < 20; ++j) m = fmaxf(m, L[g * 20 + j]);
            gmax[g] = m;
            mx = fmaxf(mx, m);
        }
        float sum = 0.f;
        for (int e = 0; e < NE; ++e) sum += __expf(L[e] - mx);
        float inv = 1.0f / sum;
        s_mx[tid]  = mx;
        s_inv[tid] = inv;

        // top-3 groups, lax.top_k tie semantics (value desc, index asc)
        unsigned sel = 0;
        float pv = 3.4e38f; int pi = -1;
        for (int it = 0; it < 3; ++it) {
            float bv = -3.4e38f; int bi = 0;
            for (int g = 0; g < 8; ++g) {
                float v = gmax[g];
                bool below = (v < pv) || (v == pv && g > pi);
                if (below && v > bv) { bv = v; bi = g; }
            }
            sel |= 1u << bi;
            pv = bv; pi = bi;
        }

        // top-6 experts within selected groups
        const int tok = row0 + tid;
        float pv2 = 3.4e38f; int pi2 = -1;
        for (int it = 0; it < 6; ++it) {
            float bv = -3.4e38f; int bi = 0;
            for (int g = 0; g < 8; ++g) {
                if (!((sel >> g) & 1u)) continue;
                for (int j = 0; j < 20; ++j) {
                    int e = g * 20 + j;
                    float v = L[e];
                    bool below = (v < pv2) || (v == pv2 && e > pi2);
                    if (below && v > bv) { bv = v; bi = e; }
                }
            }
            pv2 = bv; pi2 = bi;
            outIdx[(size_t)tok * 6 + it] = (float)bi;
            outW[(size_t)tok * 6 + it]   = __expf(bv - mx) * inv * 16.0f;
            atomicAdd(&s_cnt[bi], 1);
        }
    }
    __syncthreads();

    // ---- per-block expert score-sum + counts -> global (batch, expert) bins ----
    if (tid < NE) {
        float ss = 0.f;
        for (int t2 = 0; t2 < BM; ++t2)
            ss += __expf(s_log[t2 * 161 + tid] - s_mx[t2]) * s_inv[t2];
        const int b = row0 >> 12;   // 4096 tokens per batch
        atomicAdd(&gssum[b * NE + tid], ss);
        atomicAdd(&gcnt[b * NE + tid], (float)s_cnt[tid]);
    }
}

__global__ __launch_bounds__(64) void aux_kernel(
    const float* __restrict__ gcnt, const float* __restrict__ gssum,
    float* __restrict__ out)
{
    const int lane = threadIdx.x;
    float part = 0.f;
    if (lane < 32) {
        const int b = lane >> 3, g = lane & 7;
        const float* cn = gcnt  + b * NE + g * 20;
        const float* sm = gssum + b * NE + g * 20;
        float s1 = 0.f, sc = 0.f, sms = 0.f;
        for (int j = 0; j < 20; ++j) {
            float ce = cn[j] * (1.0f / 153.6f);   // counts / (s*k/E)
            float ms = sm[j] * (1.0f / 4096.0f);  // mean over s
            s1  += ce * ms;
            sc  += cn[j];
            sms += ms;
        }
        float ceg = sc * (1.0f / 153.6f) * (1.0f / 20.0f);
        float msg = sms * (1.0f / 20.0f);
        float ce2 = sc * (1.0f / 1536.0f);        // counts_g / (M*s/G)
        part = s1 + ceg * msg + ce2 * msg;
    }
#pragma unroll
    for (int off = 32; off > 0; off >>= 1) part += __shfl_down(part, off);
    if (lane == 0) out[0] = part * (0.001f * 0.25f);  // ALPHA * mean over B=4
}

extern "C" void kernel_launch(void* const* d_in, const int* in_sizes, int n_in,
                              void* d_out, int out_size, void* d_ws, size_t ws_size,
                              hipStream_t stream)
{
    (void)in_sizes; (void)n_in; (void)out_size; (void)ws_size;
    const float* x = (const float*)d_in[0];
    const float* w = (const float*)d_in[1];
    float* out = (float*)d_out;

    _Float16* Wf  = (_Float16*)d_ws;                  // [128][2][10][64][8] halves
    float* gcnt  = (float*)(Wf + (size_t)NE * H * 2); // [4][160]
    float* gssum = gcnt + 4 * NE;                     // [4][160]

    hipMemsetAsync(gcnt, 0, 2 * 4 * NE * sizeof(float), stream);

    prep_kernel<<<(NE * H / 8) / 256, 256, 0, stream>>>(w, Wf);
    gate_kernel<<<16384 / BM, TPB, 0, stream>>>(
        x, Wf, out, out + 98304, gcnt, gssum);
    aux_kernel<<<1, 64, 0, stream>>>(gcnt, gssum, out + 196608);
}

// Round 15
// 207.390 us; speedup vs baseline: 1.7707x; 1.7707x over previous
//
#include <hip/hip_runtime.h>

typedef _Float16 half8 __attribute__((ext_vector_type(8)));
typedef float f32x4 __attribute__((ext_vector_type(4)));

#define H    4096
#define NE   160
#define BM   32
#define TPB  512
#define NIT  64            // iterations; each stages+consumes 2 k-steps (K = 128 x 32)

// d_out layout (all float32): [0,98304) topk_idx, [98304,196608) topk_weight, [196608] aux_loss

// ---- prep: w[160][4096] fp32 -> k-step-major fragment pairs (w*64 = hi + lo/2048) ----
__global__ __launch_bounds__(256) void prep_kernel(
    const float* __restrict__ w, _Float16* __restrict__ Wf)
{
    int F    = blockIdx.x * 256 + threadIdx.x;   // 0..81919
    int lane = F & 63;
    int t10  = (F >> 6) % 10;
    int ks   = F / 640;
    int e    = t10 * 16 + (lane & 15);
    int k0   = ks * 32 + (lane >> 4) * 8;
    const float* p = w + (size_t)e * H + k0;
    float4 v0 = *(const float4*)p;
    float4 v1 = *(const float4*)(p + 4);
    float vv[8] = {v0.x, v0.y, v0.z, v0.w, v1.x, v1.y, v1.z, v1.w};
    half8 h0, h1;
#pragma unroll
    for (int j = 0; j < 8; ++j) {
        float s = vv[j] * 64.f;
        _Float16 a = (_Float16)s;
        h0[j] = a;
        h1[j] = (_Float16)((s - (float)a) * 2048.f);
    }
    half8* out = (half8*)Wf;
    out[(ks * 20 + t10) * 64 + lane]      = h0;   // hi
    out[(ks * 20 + 10 + t10) * 64 + lane] = h1;   // lo
}

#define GLOAD_LDS(SRC, DST)                                                    \
    __builtin_amdgcn_global_load_lds(                                          \
        (const __attribute__((address_space(1))) unsigned int*)(SRC),          \
        (__attribute__((address_space(3))) unsigned int*)(DST), 16, 0, 0)

#define CONVERT(U0, U1)                                                        \
    do {                                                                       \
        float v0=U0.x, v1=U0.y, v2=U0.z, v3=U0.w;                              \
        float v4=U1.x, v5=U1.y, v6=U1.z, v7=U1.w;                              \
        _Float16 h;                                                            \
        h=(_Float16)v0; a0[0]=h; a1[0]=(_Float16)((v0-(float)h)*2048.f);       \
        h=(_Float16)v1; a0[1]=h; a1[1]=(_Float16)((v1-(float)h)*2048.f);       \
        h=(_Float16)v2; a0[2]=h; a1[2]=(_Float16)((v2-(float)h)*2048.f);       \
        h=(_Float16)v3; a0[3]=h; a1[3]=(_Float16)((v3-(float)h)*2048.f);       \
        h=(_Float16)v4; a0[4]=h; a1[4]=(_Float16)((v4-(float)h)*2048.f);       \
        h=(_Float16)v5; a0[5]=h; a1[5]=(_Float16)((v5-(float)h)*2048.f);       \
        h=(_Float16)v6; a0[6]=h; a1[6]=(_Float16)((v6-(float)h)*2048.f);       \
        h=(_Float16)v7; a0[7]=h; a1[7]=(_Float16)((v7-(float)h)*2048.f);       \
    } while (0)

__global__ __launch_bounds__(TPB) void gate_kernel(
    const float* __restrict__ x, const _Float16* __restrict__ Wf,
    float* __restrict__ outIdx, float* __restrict__ outW,
    float* __restrict__ gcnt, float* __restrict__ gssum)
{
    __shared__ __align__(16) _Float16 s_w[2560 * 8];   // 40 KB W chunk (2 k-steps)
    __shared__ __align__(16) float    s_x[32 * 128];   // 16 KB x tile (4 k-steps, swizzled)
    __shared__ float s_mx[BM], s_inv[BM];
    __shared__ int   s_cnt[NE];
    float* s_log = (float*)s_w;   // [32][161] = 20608 B, aliases W stage after the loop

    const int tid  = threadIdx.x;
    const int lane = tid & 63;
    const int wv   = tid >> 6;        // 8 waves: kh(2) x mh(2) x nh(2)
    const int kh   = wv >> 2;
    const int mh   = (wv >> 1) & 1;
    const int nh   = wv & 1;
    const int row0 = blockIdx.x * BM;

    if (tid < NE) s_cnt[tid] = 0;

    // each wave: 16 rows x 80 cols, k-steps 2it+kh
    f32x4 accH[5], accL[5];
#pragma unroll
    for (int t = 0; t < 5; ++t) { accH[t] = (f32x4){0,0,0,0}; accL[t] = (f32x4){0,0,0,0}; }

    const int sbase = kh * 1280 + nh * 320 + lane;   // half8 index of first hi W frag
    const int arow  = mh * 16 + (lane & 15);         // this lane's token row (0..31)
    const int r7    = arow & 7;
    const int q2    = (lane >> 4) * 2;               // 16B-chunk offset within k-step

    // x staging mapping: 1024 16B-units = [32 rows][32 chunks]; 2 rounds of 512
    const int strow = tid >> 5;          // rows 0..15 (round 0), 16..31 (round 1 adds 16)
    const int stj   = tid & 31;          // chunk within row

    for (int it = 0; it < NIT; ++it) {
        __syncthreads();   // all reads of s_w (and s_x when even) complete

        if ((it & 1) == 0) {
            // stage x tile xt = it/2: 32 rows x 512B contiguous, source-swizzled
            const int xt = it >> 1;
#pragma unroll
            for (int ph = 0; ph < 2; ++ph) {
                int row = strow + ph * 16;
                const float* src = x + (size_t)(row0 + row) * H + xt * 128
                                   + ((stj ^ (row & 7)) << 2);
                GLOAD_LDS(src, s_x + (ph * 512 + tid) * 4);
            }
        }
        // stage W chunk (2 k-steps, 40 KB, 5 DMA rounds)
        {
            const _Float16* src = Wf + ((size_t)it * 2560 + tid) * 8;
            _Float16*       dst = s_w + (size_t)tid * 8;
#pragma unroll
            for (int i = 0; i < 5; ++i)
                GLOAD_LDS(src + i * 4096, dst + i * 4096);
        }
        __syncthreads();   // drain: W chunk (+ x tile) resident

        // x fragment from LDS (k-step ts within the 4-k-step tile)
        const int ts = (it & 1) * 2 + kh;
        const int j0 = ts * 8 + q2;
        float4 u0 = *(const float4*)(s_x + arow * 128 + ((j0 ^ r7) << 2));
        float4 u1 = *(const float4*)(s_x + arow * 128 + (((j0 + 1) ^ r7) << 2));

        const half8* B = (const half8*)s_w + sbase;
        half8 b0[5], b1[5];
#pragma unroll
        for (int t = 0; t < 5; ++t) { b0[t] = B[t * 64]; b1[t] = B[640 + t * 64]; }

        half8 a0, a1;
        CONVERT(u0, u1);
#pragma unroll
        for (int t = 0; t < 5; ++t) {
            accH[t] = __builtin_amdgcn_mfma_f32_16x16x32_f16(a0, b0[t], accH[t], 0, 0, 0);
            accL[t] = __builtin_amdgcn_mfma_f32_16x16x32_f16(a1, b0[t], accL[t], 0, 0, 0);
            accL[t] = __builtin_amdgcn_mfma_f32_16x16x32_f16(a0, b1[t], accL[t], 0, 0, 0);
        }
    }

    __syncthreads();   // all reads of s_w done; s_log may overwrite it

    // ---- K-combine into s_log; C layout col=lane&15, row=(lane>>4)*4+reg ----
    const int crow  = mh * 16 + (lane >> 4) * 4;
    const int ccol0 = nh * 80 + (lane & 15);
    if (kh == 0) {
#pragma unroll
        for (int t = 0; t < 5; ++t)
#pragma unroll
            for (int r = 0; r < 4; ++r)
                s_log[(crow + r) * 161 + ccol0 + t * 16] =
                    (accH[t][r] + accL[t][r] * (1.0f / 2048.f)) * (1.0f / 64.f);
    }
    __syncthreads();
    if (kh == 1) {
#pragma unroll
        for (int t = 0; t < 5; ++t)
#pragma unroll
            for (int r = 0; r < 4; ++r)
                s_log[(crow + r) * 161 + ccol0 + t * 16] +=
                    (accH[t][r] + accL[t][r] * (1.0f / 2048.f)) * (1.0f / 64.f);
    }
    __syncthreads();

    // ---- per-token softmax + group top-3 + expert top-6 (threads 0..31) ----
    if (tid < BM) {
        const float* L = &s_log[tid * 161];
        float gmax[8];
        float mx = -3.4e38f;
#pragma unroll
        for (int g = 0; g < 8; ++g) {
            float m = L[g * 20];
            for (int j = 1; j < 20; ++j) m = fmaxf(m, L[g * 20 + j]);
            gmax[g] = m;
            mx = fmaxf(mx, m);
        }
        float sum = 0.f;
        for (int e = 0; e < NE; ++e) sum += __expf(L[e] - mx);
        float inv = 1.0f / sum;
        s_mx[tid]  = mx;
        s_inv[tid] = inv;

        // top-3 groups, lax.top_k tie semantics (value desc, index asc)
        unsigned sel = 0;
        float pv = 3.4e38f; int pi = -1;
        for (int it = 0; it < 3; ++it) {
            float bv = -3.4e38f; int bi = 0;
            for (int g = 0; g < 8; ++g) {
                float v = gmax[g];
                bool below = (v < pv) || (v == pv && g > pi);
                if (below && v > bv) { bv = v; bi = g; }
            }
            sel |= 1u << bi;
            pv = bv; pi = bi;
        }

        // top-6 experts within selected groups
        const int tok = row0 + tid;
        float pv2 = 3.4e38f; int pi2 = -1;
        for (int it = 0; it < 6; ++it) {
            float bv = -3.4e38f; int bi = 0;
            for (int g = 0; g < 8; ++g) {
                if (!((sel >> g) & 1u)) continue;
                for (int j = 0; j < 20; ++j) {
                    int e = g * 20 + j;
                    float v = L[e];
                    bool below = (v < pv2) || (v == pv2 && e > pi2);
                    if (below && v > bv) { bv = v; bi = e; }
                }
            }
            pv2 = bv; pi2 = bi;
            outIdx[(size_t)tok * 6 + it] = (float)bi;
            outW[(size_t)tok * 6 + it]   = __expf(bv - mx) * inv * 16.0f;
            atomicAdd(&s_cnt[bi], 1);
        }
    }
    __syncthreads();

    // ---- per-block expert score-sum + counts -> global (batch, expert) bins ----
    if (tid < NE) {
        float ss = 0.f;
        for (int t2 = 0; t2 < BM; ++t2)
            ss += __expf(s_log[t2 * 161 + tid] - s_mx[t2]) * s_inv[t2];
        const int b = row0 >> 12;   // 4096 tokens per batch
        atomicAdd(&gssum[b * NE + tid], ss);
        atomicAdd(&gcnt[b * NE + tid], (float)s_cnt[tid]);
    }
}

__global__ __launch_bounds__(64) void aux_kernel(
    const float* __restrict__ gcnt, const float* __restrict__ gssum,
    float* __restrict__ out)
{
    const int lane = threadIdx.x;
    float part = 0.f;
    if (lane < 32) {
        const int b = lane >> 3, g = lane & 7;
        const float* cn = gcnt  + b * NE + g * 20;
        const float* sm = gssum + b * NE + g * 20;
        float s1 = 0.f, sc = 0.f, sms = 0.f;
        for (int j = 0; j < 20; ++j) {
            float ce = cn[j] * (1.0f / 153.6f);   // counts / (s*k/E)
            float ms = sm[j] * (1.0f / 4096.0f);  // mean over s
            s1  += ce * ms;
            sc  += cn[j];
            sms += ms;
        }
        float ceg = sc * (1.0f / 153.6f) * (1.0f / 20.0f);
        float msg = sms * (1.0f / 20.0f);
        float ce2 = sc * (1.0f / 1536.0f);        // counts_g / (M*s/G)
        part = s1 + ceg * msg + ce2 * msg;
    }
#pragma unroll
    for (int off = 32; off > 0; off >>= 1) part += __shfl_down(part, off);
    if (lane == 0) out[0] = part * (0.001f * 0.25f);  // ALPHA * mean over B=4
}

extern "C" void kernel_launch(void* const* d_in, const int* in_sizes, int n_in,
                              void* d_out, int out_size, void* d_ws, size_t ws_size,
                              hipStream_t stream)
{
    (void)in_sizes; (void)n_in; (void)out_size; (void)ws_size;
    const float* x = (const float*)d_in[0];
    const float* w = (const float*)d_in[1];
    float* out = (float*)d_out;

    _Float16* Wf  = (_Float16*)d_ws;                  // [128][2][10][64][8] halves
    float* gcnt  = (float*)(Wf + (size_t)NE * H * 2); // [4][160]
    float* gssum = gcnt + 4 * NE;                     // [4][160]

    hipMemsetAsync(gcnt, 0, 2 * 4 * NE * sizeof(float), stream);

    prep_kernel<<<(NE * H / 8) / 256, 256, 0, stream>>>(w, Wf);
    gate_kernel<<<16384 / BM, TPB, 0, stream>>>(
        x, Wf, out, out + 98304, gcnt, gssum);
    aux_kernel<<<1, 64, 0, stream>>>(gcnt, gssum, out + 196608);
}

// Round 16
// 195.513 us; speedup vs baseline: 1.8783x; 1.0607x over previous
//
#include <hip/hip_runtime.h>

typedef _Float16 half8 __attribute__((ext_vector_type(8)));
typedef float f32x4 __attribute__((ext_vector_type(4)));

#define H    4096
#define NE   160
#define BM   64
#define TPB  1024
#define NIT  64            // iterations; each consumes 2 k-steps (K = 128 x 32)

// d_out layout (all float32): [0,98304) topk_idx, [98304,196608) topk_weight, [196608] aux_loss

// ---- prep: w[160][4096] fp32 -> k-step-major fragment pairs (w*64 = hi + lo/2048) ----
// half8 index for (ks, h, t10, lane): (ks*20 + h*10 + t10)*64 + lane
// holds expert e = t10*16 + (lane&15), k = ks*32 + (lane>>4)*8 .. +8
__global__ __launch_bounds__(256) void prep_kernel(
    const float* __restrict__ w, _Float16* __restrict__ Wf)
{
    int F    = blockIdx.x * 256 + threadIdx.x;   // 0..81919
    int lane = F & 63;
    int t10  = (F >> 6) % 10;
    int ks   = F / 640;
    int e    = t10 * 16 + (lane & 15);
    int k0   = ks * 32 + (lane >> 4) * 8;
    const float* p = w + (size_t)e * H + k0;
    float4 v0 = *(const float4*)p;
    float4 v1 = *(const float4*)(p + 4);
    float vv[8] = {v0.x, v0.y, v0.z, v0.w, v1.x, v1.y, v1.z, v1.w};
    half8 h0, h1;
#pragma unroll
    for (int j = 0; j < 8; ++j) {
        float s = vv[j] * 64.f;
        _Float16 a = (_Float16)s;
        h0[j] = a;
        h1[j] = (_Float16)((s - (float)a) * 2048.f);
    }
    half8* out = (half8*)Wf;
    out[(ks * 20 + t10) * 64 + lane]      = h0;   // hi
    out[(ks * 20 + 10 + t10) * 64 + lane] = h1;   // lo
}

#define GLOAD_LDS(SRC, DST)                                                    \
    __builtin_amdgcn_global_load_lds(                                          \
        (const __attribute__((address_space(1))) unsigned int*)(SRC),          \
        (__attribute__((address_space(3))) unsigned int*)(DST), 16, 0, 0)

// stage W batch ITN (2 k-steps, 40 KB = 2560 16B-units) into s_w + WOFF halves
#define STAGE_W(ITN, WOFF)                                                     \
    do {                                                                       \
        const _Float16* _s = Wf + ((size_t)(ITN) * 2560 + tid) * 8;            \
        GLOAD_LDS(_s,            s_w + (WOFF) + (size_t)tid * 8);              \
        GLOAD_LDS(_s + 8192,     s_w + (WOFF) + (size_t)(tid + 1024) * 8);     \
        if (tid < 512)                                                         \
            GLOAD_LDS(_s + 16384, s_w + (WOFF) + (size_t)(tid + 2048) * 8);    \
    } while (0)

// stage x batch ITN (64 rows x 64 floats, source-swizzled) into s_x + XOFF floats
#define STAGE_X(ITN, XOFF)                                                     \
    do {                                                                       \
        int _row = tid >> 4, _ch = tid & 15;                                   \
        const float* _s = x + (size_t)(row0 + _row) * H + (ITN) * 64           \
                          + ((_ch ^ (_row & 7)) << 2);                         \
        GLOAD_LDS(_s, s_x + (XOFF) + tid * 4);                                 \
    } while (0)

#define CONVERT(U0, U1)                                                        \
    do {                                                                       \
        float v0=U0.x, v1=U0.y, v2=U0.z, v3=U0.w;                              \
        float v4=U1.x, v5=U1.y, v6=U1.z, v7=U1.w;                              \
        _Float16 h;                                                            \
        h=(_Float16)v0; a0[0]=h; a1[0]=(_Float16)((v0-(float)h)*2048.f);       \
        h=(_Float16)v1; a0[1]=h; a1[1]=(_Float16)((v1-(float)h)*2048.f);       \
        h=(_Float16)v2; a0[2]=h; a1[2]=(_Float16)((v2-(float)h)*2048.f);       \
        h=(_Float16)v3; a0[3]=h; a1[3]=(_Float16)((v3-(float)h)*2048.f);       \
        h=(_Float16)v4; a0[4]=h; a1[4]=(_Float16)((v4-(float)h)*2048.f);       \
        h=(_Float16)v5; a0[5]=h; a1[5]=(_Float16)((v5-(float)h)*2048.f);       \
        h=(_Float16)v6; a0[6]=h; a1[6]=(_Float16)((v6-(float)h)*2048.f);       \
        h=(_Float16)v7; a0[7]=h; a1[7]=(_Float16)((v7-(float)h)*2048.f);       \
    } while (0)

// consume buffers at WOFF (halves) / XOFF (floats): 12 ds_read + convert + 15 MFMA
#define COMPUTE(WOFF, XOFF)                                                    \
    do {                                                                       \
        const float* _xr = s_x + (XOFF) + arow * 64;                           \
        float4 u0 = *(const float4*)(_xr + ((ch0 ^ r7) << 2));                 \
        float4 u1 = *(const float4*)(_xr + ((ch1 ^ r7) << 2));                 \
        const half8* B = (const half8*)(s_w + (WOFF)) + sbase;                 \
        half8 b0[5], b1[5];                                                    \
        _Pragma("unroll")                                                      \
        for (int _t = 0; _t < 5; ++_t) {                                       \
            b0[_t] = B[_t * 64];                                               \
            b1[_t] = B[640 + _t * 64];                                         \
        }                                                                      \
        half8 a0, a1;                                                          \
        CONVERT(u0, u1);                                                       \
        _Pragma("unroll")                                                      \
        for (int _t = 0; _t < 5; ++_t) {                                       \
            accH[_t] = __builtin_amdgcn_mfma_f32_16x16x32_f16(a0, b0[_t], accH[_t], 0, 0, 0); \
            accL[_t] = __builtin_amdgcn_mfma_f32_16x16x32_f16(a1, b0[_t], accL[_t], 0, 0, 0); \
            accL[_t] = __builtin_amdgcn_mfma_f32_16x16x32_f16(a0, b1[_t], accL[_t], 0, 0, 0); \
        }                                                                      \
    } while (0)

__global__ __launch_bounds__(TPB) void gate_kernel(
    const float* __restrict__ x, const _Float16* __restrict__ Wf,
    float* __restrict__ outIdx, float* __restrict__ outW,
    float* __restrict__ gcnt, float* __restrict__ gssum)
{
    __shared__ __align__(16) _Float16 s_w[2 * 2560 * 8];   // 80 KB W double-buffer
    __shared__ __align__(16) float    s_x[2 * 4096];       // 32 KB x double-buffer
    __shared__ float s_mx[BM], s_inv[BM];
    __shared__ int   s_cnt[NE];
    float* s_log = (float*)s_w;   // [64][161] = 41 KB, aliases W stage after the loop

    const int tid  = threadIdx.x;
    const int lane = tid & 63;
    const int wv   = tid >> 6;        // 16 waves: kh(2) x mh(4) x nh(2)
    const int kh   = wv >> 3;
    const int mh   = (wv >> 1) & 3;
    const int nh   = wv & 1;
    const int row0 = blockIdx.x * BM;

    if (tid < NE) s_cnt[tid] = 0;

    // each wave: 16 rows x 80 cols, k-step 2it+kh
    f32x4 accH[5], accL[5];
#pragma unroll
    for (int t = 0; t < 5; ++t) { accH[t] = (f32x4){0,0,0,0}; accL[t] = (f32x4){0,0,0,0}; }

    const int sbase = kh * 1280 + nh * 320 + lane;   // half8 index of first hi W frag
    const int arow  = mh * 16 + (lane & 15);         // token row 0..63
    const int r7    = arow & 7;
    const int ch0   = kh * 8 + (lane >> 4) * 2;      // 16B chunk of k-step start
    const int ch1   = ch0 + 1;

    // prologue: batch 0 into buffer 0, drain
    STAGE_W(0, 0);
    STAGE_X(0, 0);
    __syncthreads();

    // T3 2-phase: issue next-batch stage BEFORE compute; single end-of-iter barrier
    for (int it = 0; it < NIT; it += 2) {
        // phase A: compute buf0, stage it+1 into buf1
        if (it + 1 < NIT) { STAGE_W(it + 1, 20480); STAGE_X(it + 1, 4096); }
        COMPUTE(0, 0);
        __syncthreads();   // drains stage of it+1; buf1 ready, buf0 free

        // phase B: compute buf1, stage it+2 into buf0
        if (it + 2 < NIT) { STAGE_W(it + 2, 0); STAGE_X(it + 2, 0); }
        COMPUTE(20480, 4096);
        __syncthreads();   // drains stage of it+2; buf0 ready, buf1 free
    }

    // ---- K-combine into s_log; C layout col=lane&15, row=(lane>>4)*4+reg ----
    const int crow  = mh * 16 + (lane >> 4) * 4;
    const int ccol0 = nh * 80 + (lane & 15);
    if (kh == 0) {
#pragma unroll
        for (int t = 0; t < 5; ++t)
#pragma unroll
            for (int r = 0; r < 4; ++r)
                s_log[(crow + r) * 161 + ccol0 + t * 16] =
                    (accH[t][r] + accL[t][r] * (1.0f / 2048.f)) * (1.0f / 64.f);
    }
    __syncthreads();
    if (kh == 1) {
#pragma unroll
        for (int t = 0; t < 5; ++t)
#pragma unroll
            for (int r = 0; r < 4; ++r)
                s_log[(crow + r) * 161 + ccol0 + t * 16] +=
                    (accH[t][r] + accL[t][r] * (1.0f / 2048.f)) * (1.0f / 64.f);
    }
    __syncthreads();

    // ---- per-token softmax + group top-3 + expert top-6 (threads 0..63) ----
    if (tid < BM) {
        const float* L = &s_log[tid * 161];
        float gmax[8];
        float mx = -3.4e38f;
#pragma unroll
        for (int g = 0; g < 8; ++g) {
            float m = L[g * 20];
            for (int j = 1; j < 20; ++j) m = fmaxf(m, L[g * 20 + j]);
            gmax[g] = m;
            mx = fmaxf(mx, m);
        }
        float sum = 0.f;
        for (int e = 0; e < NE; ++e) sum += __expf(L[e] - mx);
        float inv = 1.0f / sum;
        s_mx[tid]  = mx;
        s_inv[tid] = inv;

        // top-3 groups, lax.top_k tie semantics (value desc, index asc)
        unsigned sel = 0;
        float pv = 3.4e38f; int pi = -1;
        for (int it = 0; it < 3; ++it) {
            float bv = -3.4e38f; int bi = 0;
            for (int g = 0; g < 8; ++g) {
                float v = gmax[g];
                bool below = (v < pv) || (v == pv && g > pi);
                if (below && v > bv) { bv = v; bi = g; }
            }
            sel |= 1u << bi;
            pv = bv; pi = bi;
        }

        // top-6 experts within selected groups
        const int tok = row0 + tid;
        float pv2 = 3.4e38f; int pi2 = -1;
        for (int it = 0; it < 6; ++it) {
            float bv = -3.4e38f; int bi = 0;
            for (int g = 0; g < 8; ++g) {
                if (!((sel >> g) & 1u)) continue;
                for (int j = 0; j < 20; ++j) {
                    int e = g * 20 + j;
                    float v = L[e];
                    bool below = (v < pv2) || (v == pv2 && e > pi2);
                    if (below && v > bv) { bv = v; bi = e; }
                }
            }
            pv2 = bv; pi2 = bi;
            outIdx[(size_t)tok * 6 + it] = (float)bi;
            outW[(size_t)tok * 6 + it]   = __expf(bv - mx) * inv * 16.0f;
            atomicAdd(&s_cnt[bi], 1);
        }
    }
    __syncthreads();

    // ---- per-block expert score-sum + counts -> global (batch, expert) bins ----
    if (tid < NE) {
        float ss = 0.f;
        for (int t2 = 0; t2 < BM; ++t2)
            ss += __expf(s_log[t2 * 161 + tid] - s_mx[t2]) * s_inv[t2];
        const int b = row0 >> 12;   // 4096 tokens per batch
        atomicAdd(&gssum[b * NE + tid], ss);
        atomicAdd(&gcnt[b * NE + tid], (float)s_cnt[tid]);
    }
}

__global__ __launch_bounds__(64) void aux_kernel(
    const float* __restrict__ gcnt, const float* __restrict__ gssum,
    float* __restrict__ out)
{
    const int lane = threadIdx.x;
    float part = 0.f;
    if (lane < 32) {
        const int b = lane >> 3, g = lane & 7;
        const float* cn = gcnt  + b * NE + g * 20;
        const float* sm = gssum + b * NE + g * 20;
        float s1 = 0.f, sc = 0.f, sms = 0.f;
        for (int j = 0; j < 20; ++j) {
            float ce = cn[j] * (1.0f / 153.6f);   // counts / (s*k/E)
            float ms = sm[j] * (1.0f / 4096.0f);  // mean over s
            s1  += ce * ms;
            sc  += cn[j];
            sms += ms;
        }
        float ceg = sc * (1.0f / 153.6f) * (1.0f / 20.0f);
        float msg = sms * (1.0f / 20.0f);
        float ce2 = sc * (1.0f / 1536.0f);        // counts_g / (M*s/G)
        part = s1 + ceg * msg + ce2 * msg;
    }
#pragma unroll
    for (int off = 32; off > 0; off >>= 1) part += __shfl_down(part, off);
    if (lane == 0) out[0] = part * (0.001f * 0.25f);  // ALPHA * mean over B=4
}

extern "C" void kernel_launch(void* const* d_in, const int* in_sizes, int n_in,
                              void* d_out, int out_size, void* d_ws, size_t ws_size,
                              hipStream_t stream)
{
    (void)in_sizes; (void)n_in; (void)out_size; (void)ws_size;
    const float* x = (const float*)d_in[0];
    const float* w = (const float*)d_in[1];
    float* out = (float*)d_out;

    _Float16* Wf  = (_Float16*)d_ws;                  // [128][2][10][64][8] halves
    float* gcnt  = (float*)(Wf + (size_t)NE * H * 2); // [4][160]
    float* gssum = gcnt + 4 * NE;                     // [4][160]

    hipMemsetAsync(gcnt, 0, 2 * 4 * NE * sizeof(float), stream);

    prep_kernel<<<(NE * H / 8) / 256, 256, 0, stream>>>(w, Wf);
    gate_kernel<<<16384 / BM, TPB, 0, stream>>>(
        x, Wf, out, out + 98304, gcnt, gssum);
    aux_kernel<<<1, 64, 0, stream>>>(gcnt, gssum, out + 196608);
}